// Round 7
// baseline (212.620 us; speedup 1.0000x reference)
//
#include <hip/hip_runtime.h>

// B=64, N=2048, DIM_IN=DIM_OUT=64, CHEB_K=3, EMBED_DIM=10
#define NN 2048
#define BB 64
#define CC 64
#define ED 10
#define KK 3
#define JJ (BB * CC)   // 4096

typedef unsigned short ushort_t;
typedef __attribute__((ext_vector_type(8))) short short8;   // 8 bf16 = 4 VGPRs
typedef __attribute__((ext_vector_type(4))) float f32x4;

typedef const __attribute__((address_space(1))) unsigned* gptr_t;
typedef __attribute__((address_space(3))) unsigned* lptr_t;
typedef __attribute__((address_space(3))) ushort_t* lsptr_t;
typedef const __attribute__((address_space(3))) short8* ls8_t;

static __device__ __forceinline__ ushort_t f2bf(float f) {
    union { float f; unsigned u; } x{f};
    unsigned r = x.u + 0x7FFF + ((x.u >> 16) & 1);  // RTN-even
    return (ushort_t)(r >> 16);
}
static __device__ __forceinline__ float bf2f(ushort_t h) {
    union { unsigned u; float f; } x;
    x.u = ((unsigned)h) << 16;
    return x.f;
}

// ---------------------------------------------------------------------------
// Kernel 1 (merged prep). Round-7 tweak: supports' E-row gather vectorized to
// float2 (rows are 40 B -> 8-B aligned), halving gather instruction count.
// ---------------------------------------------------------------------------
__global__ __launch_bounds__(256) void prep_kernel(const float* __restrict__ E,
                                                   const float* __restrict__ x,
                                                   const float* __restrict__ Wp,
                                                   ushort_t* __restrict__ Ab,
                                                   ushort_t* __restrict__ xT,
                                                   ushort_t* __restrict__ xN,
                                                   ushort_t* __restrict__ WpT) {
    const int bid = blockIdx.x;
    const int tid = threadIdx.x;

    __shared__ float tb[64][68];
    __shared__ float red[8];

    if (bid < NN) {
        const int n = bid;
        float en[ED];
#pragma unroll
        for (int d = 0; d < ED; ++d) en[d] = E[n * ED + d];

        float sv[NN / 256];
        float lmax = 0.0f;
#pragma unroll
        for (int j = 0; j < NN / 256; ++j) {
            const int m = tid + j * 256;
            const float2* Em2 = (const float2*)(E + m * ED);  // 8-B aligned
            float dot = 0.0f;
#pragma unroll
            for (int d2 = 0; d2 < ED / 2; ++d2) {
                const float2 v = Em2[d2];
                dot += en[2 * d2] * v.x + en[2 * d2 + 1] * v.y;
            }
            float s = fmaxf(dot, 0.0f);
            sv[j] = s;
            lmax = fmaxf(lmax, s);
        }
#pragma unroll
        for (int off = 32; off > 0; off >>= 1) lmax = fmaxf(lmax, __shfl_down(lmax, off, 64));
        if ((tid & 63) == 0) red[tid >> 6] = lmax;
        __syncthreads();
        const float bmax = fmaxf(fmaxf(red[0], red[1]), fmaxf(red[2], red[3]));

        float lsum = 0.0f;
#pragma unroll
        for (int j = 0; j < NN / 256; ++j) {
            sv[j] = __expf(sv[j] - bmax);
            lsum += sv[j];
        }
#pragma unroll
        for (int off = 32; off > 0; off >>= 1) lsum += __shfl_down(lsum, off, 64);
        if ((tid & 63) == 0) red[4 + (tid >> 6)] = lsum;
        __syncthreads();
        const float inv = 1.0f / (red[4] + red[5] + red[6] + red[7]);

#pragma unroll
        for (int j = 0; j < NN / 256; ++j) {
            Ab[(size_t)n * NN + tid + j * 256] = f2bf(sv[j] * inv);
        }
    } else if (bid < 2 * NN) {
        const int t = bid - NN;
        const int n0 = (t & 31) * 64;
        const int b = t >> 5;

#pragma unroll
        for (int l = 0; l < 4; ++l) {
            const int idx = tid + l * 256;
            const int nn = idx >> 4;
            const int c4 = (idx & 15) << 2;
            const float4 v = *(const float4*)(x + ((size_t)b * NN + n0 + nn) * CC + c4);
            tb[c4 + 0][nn] = v.x;
            tb[c4 + 1][nn] = v.y;
            tb[c4 + 2][nn] = v.z;
            tb[c4 + 3][nn] = v.w;
        }
        __syncthreads();

#pragma unroll
        for (int l = 0; l < 2; ++l) {
            const int idx = tid + l * 256;
            const int c = idx >> 3;
            const int ch = (idx & 7) << 3;
            ushort_t pack[8];
#pragma unroll
            for (int e = 0; e < 8; ++e) pack[e] = f2bf(tb[c][ch + e]);
            *(float4*)(xT + (size_t)(b * 64 + c) * NN + n0 + ch) = *(float4*)pack;
        }
#pragma unroll
        for (int l = 0; l < 2; ++l) {
            const int idx = tid + l * 256;
            const int nn = idx >> 3;
            const int cg = (idx & 7) << 3;
            ushort_t pack[8];
#pragma unroll
            for (int e = 0; e < 8; ++e) pack[e] = f2bf(tb[cg + e][nn]);
            *(float4*)(xN + (size_t)(n0 + nn) * JJ + b * 64 + cg) = *(float4*)pack;
        }
    } else {
        const int dk = bid - 2 * NN;
        const float* src = Wp + (size_t)dk * CC * CC;

#pragma unroll
        for (int l = 0; l < 4; ++l) {
            const int idx = tid + l * 256;
            const int i = idx >> 4;
            const int o4 = (idx & 15) << 2;
            const float4 v = *(const float4*)(src + i * CC + o4);
            tb[o4 + 0][i] = v.x;
            tb[o4 + 1][i] = v.y;
            tb[o4 + 2][i] = v.z;
            tb[o4 + 3][i] = v.w;
        }
        __syncthreads();

#pragma unroll
        for (int l = 0; l < 2; ++l) {
            const int idx = tid + l * 256;
            const int o = idx >> 3;
            const int ic = (idx & 7) << 3;
            ushort_t pack[8];
#pragma unroll
            for (int e = 0; e < 8; ++e) pack[e] = f2bf(tb[o][ic + e]);
            *(float4*)(WpT + (size_t)dk * CC * CC + o * CC + ic) = *(float4*)pack;
        }
    }
}

// ---------------------------------------------------------------------------
// Kernel 2: rolled NT-GEMM, 128x256 tile, now 4 WAVES of 64x128 (256 thr).
// Round-6 post-mortem: 8 waves of 64x64 -> 128 ds_read_b128/tile/CU (1536cy)
// vs 256 MFMA (1242cy): LDS pipe bound + 8-deep read queuing = 3150 cyc/tile.
// 64x128 wave tile: reads/tile/CU = 96 (1152cy) < MFMA (1242cy) -> MFMA-bound.
// Each wave's 24 reads hide under its own deferred 32-MFMA cluster (roll).
// 3-buffer LDS (3 x 48 KB), 1 barrier/tile, counted vmcnt(12). Ledger:
// tile t top outstanding = {t?, t+1} = 24 loads -> vmcnt(12) ==> buf(t)
// landed (vmcnt(0) at t=31). Stage t+2 overwrites buf(t-1): its tail reads
// complete before their consuming MFMA_C1 (compiler lgkm) which precedes the
// t-top barrier; stage issues after that barrier. Same WAR proof as round 6.
// Staging map (256 thr, 12 x 16B loads/tile): load i adds 32 rows in global
// and 2048 ushorts in LDS; swizzle involution unchanged from round 6.
// ---------------------------------------------------------------------------
#define STAGE_AB(bp, kt) do {                                                               \
    _Pragma("unroll") for (int i_ = 0; i_ < 4; ++i_)                                        \
        __builtin_amdgcn_global_load_lds(                                                   \
            (gptr_t)(srcA + (size_t)(kt) * 64 + (size_t)i_ * 32 * NN),                      \
            (lptr_t)&(bp)[dstoff + i_ * 2048], 16, 0, 0);                                   \
    _Pragma("unroll") for (int i_ = 0; i_ < 8; ++i_)                                        \
        __builtin_amdgcn_global_load_lds(                                                   \
            (gptr_t)(srcB + (size_t)(kt) * 64 + (size_t)i_ * 32 * NN),                      \
            (lptr_t)&(bp)[8192 + dstoff + i_ * 2048], 16, 0, 0);                            \
} while (0)

#define LDA_ALL(bp) do {                                                                    \
    _Pragma("unroll") for (int mi_ = 0; mi_ < 4; ++mi_)                                     \
    _Pragma("unroll") for (int ks_ = 0; ks_ < 2; ++ks_)                                     \
        a[mi_][ks_] = *(ls8_t)&(bp)[(aRG + mi_) * 1024 + ks_ * 512 + rdofs];                \
} while (0)

#define LDB_LO(bp) do {                                                                     \
    _Pragma("unroll") for (int ni_ = 0; ni_ < 4; ++ni_)                                     \
    _Pragma("unroll") for (int ks_ = 0; ks_ < 2; ++ks_)                                     \
        b[ni_][ks_] = *(ls8_t)&(bp)[8192 + (bRG + ni_) * 1024 + ks_ * 512 + rdofs];         \
} while (0)

#define LDB_HI(bp) do {                                                                     \
    _Pragma("unroll") for (int ni_ = 4; ni_ < 8; ++ni_)                                     \
    _Pragma("unroll") for (int ks_ = 0; ks_ < 2; ++ks_)                                     \
        b[ni_][ks_] = *(ls8_t)&(bp)[8192 + (bRG + ni_) * 1024 + ks_ * 512 + rdofs];         \
} while (0)

// cluster c covers ni = 4c..4c+3: 4 mi x 4 ni x 2 ks = 32 MFMAs
#define MFMA_C(c) do {                                                                      \
    __builtin_amdgcn_s_setprio(1);                                                          \
    _Pragma("unroll") for (int mi_ = 0; mi_ < 4; ++mi_)                                     \
    _Pragma("unroll") for (int nn_ = 0; nn_ < 4; ++nn_) {                                   \
        acc[mi_][(c) * 4 + nn_] = __builtin_amdgcn_mfma_f32_16x16x32_bf16(                  \
            a[mi_][0], b[(c) * 4 + nn_][0], acc[mi_][(c) * 4 + nn_], 0, 0, 0);              \
        acc[mi_][(c) * 4 + nn_] = __builtin_amdgcn_mfma_f32_16x16x32_bf16(                  \
            a[mi_][1], b[(c) * 4 + nn_][1], acc[mi_][(c) * 4 + nn_], 0, 0, 0);              \
    }                                                                                       \
    __builtin_amdgcn_s_setprio(0);                                                          \
} while (0)

template <int MODE>
__global__ __launch_bounds__(256, 1) void gemm_roll(const ushort_t* __restrict__ A,
                                                    const ushort_t* __restrict__ Bt,
                                                    const ushort_t* __restrict__ Zn,
                                                    ushort_t* __restrict__ Ct,
                                                    ushort_t* __restrict__ Cn) {
    // bijective XCD swizzle (256 % 8 == 0)
    int bid = blockIdx.x;
    bid = (bid & 7) * 32 + (bid >> 3);
    const int bx = bid & 15;        // j-tile (BN=256)
    const int by = bid >> 4;        // m-tile (BM=128)
    const int j0 = bx * 256;
    const int m0 = by * 128;

    const int tid = threadIdx.x;
    const int w = tid >> 6;         // wave 0..3 (2M x 2N)
    const int lane = tid & 63;
    const int l16 = lane & 15;
    const int quad = lane >> 4;
    const int wm = (w >> 1) * 64;   // wave rows [wm, wm+64)
    const int wn = (w & 1) * 128;   // wave cols [wn, wn+128)
    const int aRG = (w >> 1) * 4;   // A subtile base (8 subtiles of 16 rows)
    const int bRG = (w & 1) * 8;    // B subtile base (16 subtiles)
    // swizzled ds_read offset (ushorts): row l16, k-chunk quad, st_16x32 XOR
    const int rdofs = l16 * 32 + ((quad * 8) ^ ((l16 & 8) * 2));

    // staging: linear LDS dest (tid*16B, +2048/load); inverse-swizzled SOURCE
    const int r16s = (tid >> 2) & 15;                 // row within 16-row subtile
    const int q4 = tid & 3;                           // 16B chunk within 32-k half
    const int cx = q4 ^ ((r16s >> 3) << 1);           // inverse st_16x32
    const int rowg0 = (tid >> 7) * 16 + r16s;         // base row (load i adds 32i)
    const int kofs = ((tid >> 6) & 1) * 32 + cx * 8;  // k element offset
    const ushort_t* srcA = A + (size_t)(m0 + rowg0) * NN + kofs;
    const ushort_t* srcB = Bt + (size_t)(j0 + rowg0) * NN + kofs;
    const int dstoff = tid * 8;

    __shared__ ushort_t lds[3][24576];  // 3 x (A 16KB | B 32KB) = 144 KB

    lsptr_t p0 = (lsptr_t)&lds[0][0];   // buf(t)
    lsptr_t p1 = (lsptr_t)&lds[1][0];   // buf(t+1)
    lsptr_t p2 = (lsptr_t)&lds[2][0];   // buf(t+2) = stage target

    f32x4 acc[4][8];
#pragma unroll
    for (int mi = 0; mi < 4; ++mi)
#pragma unroll
        for (int ni = 0; ni < 8; ++ni) acc[mi][ni] = (f32x4){0.f, 0.f, 0.f, 0.f};

    short8 a[4][2], b[8][2];

    // Prologue: stage t0 (oldest) then t1. Loop-top vmcnt(12) drains t0.
    STAGE_AB(p0, 0);
    STAGE_AB(p1, 1);

#pragma unroll 1
    for (int t = 0; t < 32; ++t) {
        // deferred cluster of tile t-1 (old a, b[4..7]) covers drain + reads
        if (t) MFMA_C(1);
        if (t < 31) { asm volatile("s_waitcnt vmcnt(12)" ::: "memory"); }
        else        { asm volatile("s_waitcnt vmcnt(0)" ::: "memory"); }
        __builtin_amdgcn_sched_barrier(0);
        __builtin_amdgcn_s_barrier();          // buf(t) collectively landed

        LDA_ALL(p0); LDB_LO(p0);               // 16 ds_reads
        if (t < 30) STAGE_AB(p2, t + 2);       // 12 global_load_lds
        asm volatile("s_waitcnt lgkmcnt(0)" ::: "memory");
        __builtin_amdgcn_sched_barrier(0);
        MFMA_C(0);                              // 32 MFMAs cover:
        LDB_HI(p0);                             // 8 tail reads (b[4..7])
        __builtin_amdgcn_sched_barrier(0);

        lsptr_t tp = p0; p0 = p1; p1 = p2; p2 = tp;  // rotate buffers
    }
    MFMA_C(1);  // tile 31's second cluster

    // Epilogue: C/D col j = l16, row m = quad*4 + r.
#pragma unroll
    for (int mi = 0; mi < 4; ++mi) {
#pragma unroll
        for (int ji = 0; ji < 8; ++ji) {
            const int j = j0 + wn + ji * 16 + l16;
            const int mb = m0 + wm + mi * 16 + quad * 4;
            if (MODE == 0) {
                ushort_t o[4];
#pragma unroll
                for (int r = 0; r < 4; ++r) o[r] = f2bf(acc[mi][ji][r]);
                *(unsigned long long*)(Ct + (size_t)j * NN + mb) = *(unsigned long long*)o;
#pragma unroll
                for (int r = 0; r < 4; ++r) Cn[(size_t)(mb + r) * JJ + j] = o[r];
            } else {
#pragma unroll
                for (int r = 0; r < 4; ++r) {
                    const float z = bf2f(Zn[(size_t)(mb + r) * JJ + j]);
                    Cn[(size_t)(mb + r) * JJ + j] = f2bf(2.0f * acc[mi][ji][r] - z);
                }
            }
        }
    }
}

#undef STAGE_AB
#undef LDA_ALL
#undef LDB_LO
#undef LDB_HI
#undef MFMA_C

// ---------------------------------------------------------------------------
// Kernel 3: MFMA epilogue (identical to the verified round-0 version).
// ---------------------------------------------------------------------------
#define XLD 200  // LDS row stride (bf16): 400 B -> 2-way bank alias (free)
__global__ __launch_bounds__(256) void out_kernel(const float* __restrict__ E,
                                                  const ushort_t* __restrict__ WpT,
                                                  const float* __restrict__ bp,
                                                  const ushort_t* __restrict__ xN,
                                                  const ushort_t* __restrict__ y1N,
                                                  const ushort_t* __restrict__ y2N,
                                                  float* __restrict__ out) {
    const int n = blockIdx.x;
    const int tid = threadIdx.x;

    __shared__ ushort_t xg[BB * XLD];
    __shared__ ushort_t Wt[CC * XLD];
    __shared__ float en_s[ED];
    __shared__ float bias_s[CC];

    if (tid < ED) en_s[tid] = E[n * ED + tid];
    __syncthreads();

    float en[ED];
#pragma unroll
    for (int d = 0; d < ED; ++d) en[d] = en_s[d];

    if (tid < CC) {
        float bsum = 0.0f;
#pragma unroll
        for (int d = 0; d < ED; ++d) bsum += en[d] * bp[d * CC + tid];
        bias_s[tid] = bsum;
    }

#pragma unroll
    for (int k = 0; k < KK; ++k) {
        const ushort_t* src = (k == 0) ? xN : (k == 1) ? y1N : y2N;
        const float4* srow = (const float4*)(src + (size_t)n * JJ);
        for (int idx = tid; idx < JJ / 8; idx += 256) {
            *(float4*)&xg[(idx >> 3) * XLD + k * 64 + ((idx & 7) << 3)] = srow[idx];
        }
    }

    for (int t = tid; t < CC * 24; t += 256) {
        const int o = t / 24;
        const int kc = t % 24;
        const int k = kc >> 3;
        const int ic = (kc & 7) << 3;
        float s[8];
#pragma unroll
        for (int e = 0; e < 8; ++e) s[e] = 0.0f;
#pragma unroll
        for (int d = 0; d < ED; ++d) {
            const float4 wv4 = *(const float4*)(WpT + ((size_t)(d * KK + k) * CC + o) * CC + ic);
            const ushort_t* wp = (const ushort_t*)&wv4;
#pragma unroll
            for (int e = 0; e < 8; ++e) s[e] += en[d] * bf2f(wp[e]);
        }
        ushort_t pack[8];
#pragma unroll
        for (int e = 0; e < 8; ++e) pack[e] = f2bf(s[e]);
        *(float4*)&Wt[o * XLD + k * 64 + ic] = *(float4*)pack;
    }
    __syncthreads();

    const int lane = tid & 63;
    const int l16 = lane & 15;
    const int quad = lane >> 4;
    const int bm = (tid >> 6) * 16;

    f32x4 acc[4];
#pragma unroll
    for (int ji = 0; ji < 4; ++ji) acc[ji] = (f32x4){0.f, 0.f, 0.f, 0.f};

#pragma unroll
    for (int kc = 0; kc < 6; ++kc) {
        const short8 av = *(const short8*)&xg[(bm + l16) * XLD + kc * 32 + quad * 8];
#pragma unroll
        for (int ji = 0; ji < 4; ++ji) {
            const short8 bv = *(const short8*)&Wt[(ji * 16 + l16) * XLD + kc * 32 + quad * 8];
            acc[ji] = __builtin_amdgcn_mfma_f32_16x16x32_bf16(av, bv, acc[ji], 0, 0, 0);
        }
    }

#pragma unroll
    for (int ji = 0; ji < 4; ++ji) {
        const int o = ji * 16 + l16;
        const float bo = bias_s[o];
#pragma unroll
        for (int r = 0; r < 4; ++r) {
            const int b = bm + quad * 4 + r;
            out[((size_t)b * NN + n) * CC + o] = acc[ji][r] + bo;
        }
    }
}
#undef XLD

// ---------------------------------------------------------------------------
// Host launch: 4 dispatches.
// Workspace (bf16): Ab 8 | xT 16 | xN 16 | y1T 16 | y1N 16 | y2N 16
//   | WpT 0.24  = 88.25 MB.
// ---------------------------------------------------------------------------
extern "C" void kernel_launch(void* const* d_in, const int* in_sizes, int n_in,
                              void* d_out, int out_size, void* d_ws, size_t ws_size,
                              hipStream_t stream) {
    const float* x  = (const float*)d_in[0];
    const float* E  = (const float*)d_in[1];
    const float* Wp = (const float*)d_in[2];
    const float* bp = (const float*)d_in[3];

    ushort_t* Ab  = (ushort_t*)d_ws;                    // [2048][2048]
    ushort_t* xT  = Ab + (size_t)NN * NN;               // [4096][2048]
    ushort_t* xN  = xT + (size_t)JJ * NN;               // [2048][4096]
    ushort_t* y1T = xN + (size_t)NN * JJ;               // [4096][2048]
    ushort_t* y1N = y1T + (size_t)JJ * NN;              // [2048][4096]
    ushort_t* y2N = y1N + (size_t)NN * JJ;              // [2048][4096]
    ushort_t* WpT = y2N + (size_t)NN * JJ;              // [30][64][64]
    float* out = (float*)d_out;

    prep_kernel<<<2 * NN + ED * KK, 256, 0, stream>>>(E, x, Wp, Ab, xT, xN, WpT);
    // y1 = A @ x : dual output (K-major + node-major)
    gemm_roll<0><<<256, 256, 0, stream>>>(Ab, xT, nullptr, y1T, y1N);
    // y2 = 2 A @ y1 - x : node-major only
    gemm_roll<1><<<256, 256, 0, stream>>>(Ab, y1T, xN, nullptr, y2N);
    out_kernel<<<NN, 256, 0, stream>>>(E, WpT, bp, xN, y1N, y2N, out);
}

// Round 9
// 208.279 us; speedup vs baseline: 1.0208x; 1.0208x over previous
//
#include <hip/hip_runtime.h>

// B=64, N=2048, DIM_IN=DIM_OUT=64, CHEB_K=3, EMBED_DIM=10
#define NN 2048
#define BB 64
#define CC 64
#define ED 10
#define KK 3
#define JJ (BB * CC)   // 4096

typedef unsigned short ushort_t;
typedef __attribute__((ext_vector_type(8))) short short8;   // 8 bf16 = 4 VGPRs
typedef __attribute__((ext_vector_type(4))) float f32x4;

typedef const __attribute__((address_space(1))) unsigned* gptr_t;
typedef __attribute__((address_space(3))) unsigned* lptr_t;
typedef __attribute__((address_space(3))) ushort_t* lsptr_t;
typedef const __attribute__((address_space(3))) short8* ls8_t;

static __device__ __forceinline__ ushort_t f2bf(float f) {
    union { float f; unsigned u; } x{f};
    unsigned r = x.u + 0x7FFF + ((x.u >> 16) & 1);  // RTN-even
    return (ushort_t)(r >> 16);
}
static __device__ __forceinline__ float bf2f(ushort_t h) {
    union { unsigned u; float f; } x;
    x.u = ((unsigned)h) << 16;
    return x.f;
}

// ---------------------------------------------------------------------------
// Kernel 1 (merged prep): round-7 version (float2 E-gather), verified.
// ---------------------------------------------------------------------------
__global__ __launch_bounds__(256) void prep_kernel(const float* __restrict__ E,
                                                   const float* __restrict__ x,
                                                   const float* __restrict__ Wp,
                                                   ushort_t* __restrict__ Ab,
                                                   ushort_t* __restrict__ xT,
                                                   ushort_t* __restrict__ xN,
                                                   ushort_t* __restrict__ WpT) {
    const int bid = blockIdx.x;
    const int tid = threadIdx.x;

    __shared__ float tb[64][68];
    __shared__ float red[8];

    if (bid < NN) {
        const int n = bid;
        float en[ED];
#pragma unroll
        for (int d = 0; d < ED; ++d) en[d] = E[n * ED + d];

        float sv[NN / 256];
        float lmax = 0.0f;
#pragma unroll
        for (int j = 0; j < NN / 256; ++j) {
            const int m = tid + j * 256;
            const float2* Em2 = (const float2*)(E + m * ED);  // 8-B aligned
            float dot = 0.0f;
#pragma unroll
            for (int d2 = 0; d2 < ED / 2; ++d2) {
                const float2 v = Em2[d2];
                dot += en[2 * d2] * v.x + en[2 * d2 + 1] * v.y;
            }
            float s = fmaxf(dot, 0.0f);
            sv[j] = s;
            lmax = fmaxf(lmax, s);
        }
#pragma unroll
        for (int off = 32; off > 0; off >>= 1) lmax = fmaxf(lmax, __shfl_down(lmax, off, 64));
        if ((tid & 63) == 0) red[tid >> 6] = lmax;
        __syncthreads();
        const float bmax = fmaxf(fmaxf(red[0], red[1]), fmaxf(red[2], red[3]));

        float lsum = 0.0f;
#pragma unroll
        for (int j = 0; j < NN / 256; ++j) {
            sv[j] = __expf(sv[j] - bmax);
            lsum += sv[j];
        }
#pragma unroll
        for (int off = 32; off > 0; off >>= 1) lsum += __shfl_down(lsum, off, 64);
        if ((tid & 63) == 0) red[4 + (tid >> 6)] = lsum;
        __syncthreads();
        const float inv = 1.0f / (red[4] + red[5] + red[6] + red[7]);

#pragma unroll
        for (int j = 0; j < NN / 256; ++j) {
            Ab[(size_t)n * NN + tid + j * 256] = f2bf(sv[j] * inv);
        }
    } else if (bid < 2 * NN) {
        const int t = bid - NN;
        const int n0 = (t & 31) * 64;
        const int b = t >> 5;

#pragma unroll
        for (int l = 0; l < 4; ++l) {
            const int idx = tid + l * 256;
            const int nn = idx >> 4;
            const int c4 = (idx & 15) << 2;
            const float4 v = *(const float4*)(x + ((size_t)b * NN + n0 + nn) * CC + c4);
            tb[c4 + 0][nn] = v.x;
            tb[c4 + 1][nn] = v.y;
            tb[c4 + 2][nn] = v.z;
            tb[c4 + 3][nn] = v.w;
        }
        __syncthreads();

#pragma unroll
        for (int l = 0; l < 2; ++l) {
            const int idx = tid + l * 256;
            const int c = idx >> 3;
            const int ch = (idx & 7) << 3;
            ushort_t pack[8];
#pragma unroll
            for (int e = 0; e < 8; ++e) pack[e] = f2bf(tb[c][ch + e]);
            *(float4*)(xT + (size_t)(b * 64 + c) * NN + n0 + ch) = *(float4*)pack;
        }
#pragma unroll
        for (int l = 0; l < 2; ++l) {
            const int idx = tid + l * 256;
            const int nn = idx >> 3;
            const int cg = (idx & 7) << 3;
            ushort_t pack[8];
#pragma unroll
            for (int e = 0; e < 8; ++e) pack[e] = f2bf(tb[cg + e][nn]);
            *(float4*)(xN + (size_t)(n0 + nn) * JJ + b * 64 + cg) = *(float4*)pack;
        }
    } else {
        const int dk = bid - 2 * NN;
        const float* src = Wp + (size_t)dk * CC * CC;

#pragma unroll
        for (int l = 0; l < 4; ++l) {
            const int idx = tid + l * 256;
            const int i = idx >> 4;
            const int o4 = (idx & 15) << 2;
            const float4 v = *(const float4*)(src + i * CC + o4);
            tb[o4 + 0][i] = v.x;
            tb[o4 + 1][i] = v.y;
            tb[o4 + 2][i] = v.z;
            tb[o4 + 3][i] = v.w;
        }
        __syncthreads();

#pragma unroll
        for (int l = 0; l < 2; ++l) {
            const int idx = tid + l * 256;
            const int o = idx >> 3;
            const int ic = (idx & 7) << 3;
            ushort_t pack[8];
#pragma unroll
            for (int e = 0; e < 8; ++e) pack[e] = f2bf(tb[o][ic + e]);
            *(float4*)(WpT + (size_t)dk * CC * CC + o * CC + ic) = *(float4*)pack;
        }
    }
}

// ---------------------------------------------------------------------------
// Kernel 2: register-pipelined NT-GEMM. Round-6 geometry (128x256 block,
// 8 waves of 64x64, 512 thr, 3-buffer LDS 144 KB, grid 256 = 1 block/CU),
// restructured so the per-tile lgkm fence is GONE:
//   body t: MFMA x32 consume frags(t) [read last body] while 16 ds_reads
//   fetch frags(t+1) into the OTHER named register set (no consumer this
//   body -> compiler issues them early; latency hides under MFMAs).
// Two tiles/iteration for fully static register sets (a0/b0, a1/b1);
// buffer pointers rotate by 2 each iteration: (p0,p1,p2) <- (p2,p0,p1).
// Ledger: 6 stage-instr/tile. Top of each body: vmcnt(0) [stage(t+1),
// issued last body, landed] + barrier (publishes cross-wave) + sched_barrier
// (keeps ds_reads below the barrier). stage(t+2) issues after the wait.
// WAR: stage(t+2) -> buf holding frags(t-1), read two bodies ago; every
// wave's reads completed before its MFMAs last body, which precede this
// body's barrier. Same proof structure as the refcheck-passed round 6.
// ---------------------------------------------------------------------------
#define STAGE_ALL(bp, kt) do {                                                              \
    __builtin_amdgcn_global_load_lds(                                                       \
        (gptr_t)(srcA + (size_t)(kt) * 64),                                                 \
        (lptr_t)&(bp)[dstoff], 16, 0, 0);                                                   \
    __builtin_amdgcn_global_load_lds(                                                       \
        (gptr_t)(srcA + (size_t)64 * NN + (size_t)(kt) * 64),                               \
        (lptr_t)&(bp)[4096 + dstoff], 16, 0, 0);                                            \
    _Pragma("unroll") for (int u_ = 0; u_ < 4; ++u_)                                        \
        __builtin_amdgcn_global_load_lds(                                                   \
            (gptr_t)(srcB + (size_t)(u_ * 64) * NN + (size_t)(kt) * 64),                    \
            (lptr_t)&(bp)[8192 + u_ * 4096 + dstoff], 16, 0, 0);                            \
} while (0)

#define READ_FRAGS(aa, bb, bp) do {                                                         \
    _Pragma("unroll") for (int mi_ = 0; mi_ < 4; ++mi_)                                     \
    _Pragma("unroll") for (int ks_ = 0; ks_ < 2; ++ks_)                                     \
        aa[mi_][ks_] = *(ls8_t)&(bp)[(aRG + mi_) * 1024 + ks_ * 512 + rdofs];               \
    _Pragma("unroll") for (int ni_ = 0; ni_ < 4; ++ni_)                                     \
    _Pragma("unroll") for (int ks_ = 0; ks_ < 2; ++ks_)                                     \
        bb[ni_][ks_] = *(ls8_t)&(bp)[8192 + (bRG + ni_) * 1024 + ks_ * 512 + rdofs];        \
} while (0)

#define MFMA_SET(aa, bb) do {                                                               \
    __builtin_amdgcn_s_setprio(1);                                                          \
    _Pragma("unroll") for (int mi_ = 0; mi_ < 4; ++mi_)                                     \
    _Pragma("unroll") for (int ni_ = 0; ni_ < 4; ++ni_) {                                   \
        acc[mi_][ni_] = __builtin_amdgcn_mfma_f32_16x16x32_bf16(                            \
            aa[mi_][0], bb[ni_][0], acc[mi_][ni_], 0, 0, 0);                                \
        acc[mi_][ni_] = __builtin_amdgcn_mfma_f32_16x16x32_bf16(                            \
            aa[mi_][1], bb[ni_][1], acc[mi_][ni_], 0, 0, 0);                                \
    }                                                                                       \
    __builtin_amdgcn_s_setprio(0);                                                          \
} while (0)

#define TILE_TOP do {                                                                       \
    asm volatile("s_waitcnt vmcnt(0)" ::: "memory");                                        \
    __builtin_amdgcn_s_barrier();                                                           \
    __builtin_amdgcn_sched_barrier(0);                                                      \
} while (0)

template <int MODE>
__global__ __launch_bounds__(512, 2) void gemm_pipe(const ushort_t* __restrict__ A,
                                                    const ushort_t* __restrict__ Bt,
                                                    const ushort_t* __restrict__ Zn,
                                                    ushort_t* __restrict__ Ct,
                                                    ushort_t* __restrict__ Cn) {
    // bijective XCD swizzle (256 % 8 == 0)
    int bid = blockIdx.x;
    bid = (bid & 7) * 32 + (bid >> 3);
    const int bx = bid & 15;        // j-tile (BN=256)
    const int by = bid >> 4;        // m-tile (BM=128)
    const int j0 = bx * 256;
    const int m0 = by * 128;

    const int tid = threadIdx.x;
    const int w = tid >> 6;
    const int lane = tid & 63;
    const int l16 = lane & 15;
    const int quad = lane >> 4;
    const int wm = (w >> 2) * 64;   // wave rows [wm, wm+64)
    const int wn = (w & 3) * 64;    // wave cols [wn, wn+64)
    const int aRG = (w >> 2) * 4;   // A subtile base (8 subtiles of 16 rows)
    const int bRG = (w & 3) * 4;    // B subtile base (16 subtiles)
    // swizzled ds_read offset (ushorts): row l16, k-chunk quad, st_16x32 XOR
    const int rdofs = l16 * 32 + ((quad * 8) ^ ((l16 & 8) * 2));

    // staging: linear LDS dest (tid*16B); inverse-swizzled SOURCE (round 6)
    const int r16s = lane >> 2;
    const int cx = (lane & 3) ^ ((r16s >> 3) << 1);
    const int rowbase = (w >> 1) * 16 + r16s;         // row within 64-row unit
    const int kofs = (w & 1) * 32 + cx * 8;
    const ushort_t* srcA = A + (size_t)(m0 + rowbase) * NN + kofs;
    const ushort_t* srcB = Bt + (size_t)(j0 + rowbase) * NN + kofs;
    const int dstoff = tid * 8;

    __shared__ ushort_t lds[3][24576];  // 3 x (A 16KB | B 32KB) = 144 KB

    lsptr_t p0 = (lsptr_t)&lds[0][0];
    lsptr_t p1 = (lsptr_t)&lds[1][0];
    lsptr_t p2 = (lsptr_t)&lds[2][0];

    f32x4 acc[4][4];
#pragma unroll
    for (int mi = 0; mi < 4; ++mi)
#pragma unroll
        for (int ni = 0; ni < 4; ++ni) acc[mi][ni] = (f32x4){0.f, 0.f, 0.f, 0.f};

    short8 a0[4][2], b0[4][2], a1[4][2], b1[4][2];

    // Prologue: stage t0, t1; vmcnt(6) -> t0 landed; read frags(t0) -> set0.
    STAGE_ALL(p0, 0);
    STAGE_ALL(p1, 1);
    asm volatile("s_waitcnt vmcnt(6)" ::: "memory");
    __builtin_amdgcn_s_barrier();
    __builtin_amdgcn_sched_barrier(0);
    READ_FRAGS(a0, b0, p0);

#pragma unroll 1
    for (int i = 0; i < 16; ++i) {
        const bool stg = (i < 15);
        // body t=2i: MFMA set0 (tile 2i); read set1 = frags(2i+1) from p1;
        // stage 2i+2 -> p2
        TILE_TOP;                       // vmcnt(0): tile 2i+1 landed; publish
        if (stg) STAGE_ALL(p2, 2 * i + 2);
        READ_FRAGS(a1, b1, p1);
        MFMA_SET(a0, b0);
        // body t=2i+1: MFMA set1 (tile 2i+1); read set0 = frags(2i+2) from p2;
        // stage 2i+3 -> p0
        TILE_TOP;                       // vmcnt(0): tile 2i+2 landed; publish
        if (stg) {
            STAGE_ALL(p0, 2 * i + 3);
            READ_FRAGS(a0, b0, p2);
        }
        MFMA_SET(a1, b1);
        // rotate by 2 tiles: (p0,p1,p2) <- (p2,p0,p1)
        lsptr_t q0 = p0, q1 = p1, q2 = p2;
        p0 = q2; p1 = q0; p2 = q1;
    }

    // Epilogue: C/D col j = l16, row m = quad*4 + r.
#pragma unroll
    for (int mi = 0; mi < 4; ++mi) {
#pragma unroll
        for (int ji = 0; ji < 4; ++ji) {
            const int j = j0 + wn + ji * 16 + l16;
            const int mb = m0 + wm + mi * 16 + quad * 4;
            if (MODE == 0) {
                ushort_t o[4];
#pragma unroll
                for (int r = 0; r < 4; ++r) o[r] = f2bf(acc[mi][ji][r]);
                *(unsigned long long*)(Ct + (size_t)j * NN + mb) = *(unsigned long long*)o;
#pragma unroll
                for (int r = 0; r < 4; ++r) Cn[(size_t)(mb + r) * JJ + j] = o[r];
            } else {
#pragma unroll
                for (int r = 0; r < 4; ++r) {
                    const float z = bf2f(Zn[(size_t)(mb + r) * JJ + j]);
                    Cn[(size_t)(mb + r) * JJ + j] = f2bf(2.0f * acc[mi][ji][r] - z);
                }
            }
        }
    }
}

#undef STAGE_ALL
#undef READ_FRAGS
#undef MFMA_SET
#undef TILE_TOP

// ---------------------------------------------------------------------------
// Kernel 3: MFMA epilogue (identical to the verified round-0 version).
// ---------------------------------------------------------------------------
#define XLD 200  // LDS row stride (bf16): 400 B -> 2-way bank alias (free)
__global__ __launch_bounds__(256) void out_kernel(const float* __restrict__ E,
                                                  const ushort_t* __restrict__ WpT,
                                                  const float* __restrict__ bp,
                                                  const ushort_t* __restrict__ xN,
                                                  const ushort_t* __restrict__ y1N,
                                                  const ushort_t* __restrict__ y2N,
                                                  float* __restrict__ out) {
    const int n = blockIdx.x;
    const int tid = threadIdx.x;

    __shared__ ushort_t xg[BB * XLD];
    __shared__ ushort_t Wt[CC * XLD];
    __shared__ float en_s[ED];
    __shared__ float bias_s[CC];

    if (tid < ED) en_s[tid] = E[n * ED + tid];
    __syncthreads();

    float en[ED];
#pragma unroll
    for (int d = 0; d < ED; ++d) en[d] = en_s[d];

    if (tid < CC) {
        float bsum = 0.0f;
#pragma unroll
        for (int d = 0; d < ED; ++d) bsum += en[d] * bp[d * CC + tid];
        bias_s[tid] = bsum;
    }

#pragma unroll
    for (int k = 0; k < KK; ++k) {
        const ushort_t* src = (k == 0) ? xN : (k == 1) ? y1N : y2N;
        const float4* srow = (const float4*)(src + (size_t)n * JJ);
        for (int idx = tid; idx < JJ / 8; idx += 256) {
            *(float4*)&xg[(idx >> 3) * XLD + k * 64 + ((idx & 7) << 3)] = srow[idx];
        }
    }

    for (int t = tid; t < CC * 24; t += 256) {
        const int o = t / 24;
        const int kc = t % 24;
        const int k = kc >> 3;
        const int ic = (kc & 7) << 3;
        float s[8];
#pragma unroll
        for (int e = 0; e < 8; ++e) s[e] = 0.0f;
#pragma unroll
        for (int d = 0; d < ED; ++d) {
            const float4 wv4 = *(const float4*)(WpT + ((size_t)(d * KK + k) * CC + o) * CC + ic);
            const ushort_t* wp = (const ushort_t*)&wv4;
#pragma unroll
            for (int e = 0; e < 8; ++e) s[e] += en[d] * bf2f(wp[e]);
        }
        ushort_t pack[8];
#pragma unroll
        for (int e = 0; e < 8; ++e) pack[e] = f2bf(s[e]);
        *(float4*)&Wt[o * XLD + k * 64 + ic] = *(float4*)pack;
    }
    __syncthreads();

    const int lane = tid & 63;
    const int l16 = lane & 15;
    const int quad = lane >> 4;
    const int bm = (tid >> 6) * 16;

    f32x4 acc[4];
#pragma unroll
    for (int ji = 0; ji < 4; ++ji) acc[ji] = (f32x4){0.f, 0.f, 0.f, 0.f};

#pragma unroll
    for (int kc = 0; kc < 6; ++kc) {
        const short8 av = *(const short8*)&xg[(bm + l16) * XLD + kc * 32 + quad * 8];
#pragma unroll
        for (int ji = 0; ji < 4; ++ji) {
            const short8 bv = *(const short8*)&Wt[(ji * 16 + l16) * XLD + kc * 32 + quad * 8];
            acc[ji] = __builtin_amdgcn_mfma_f32_16x16x32_bf16(av, bv, acc[ji], 0, 0, 0);
        }
    }

#pragma unroll
    for (int ji = 0; ji < 4; ++ji) {
        const int o = ji * 16 + l16;
        const float bo = bias_s[o];
#pragma unroll
        for (int r = 0; r < 4; ++r) {
            const int b = bm + quad * 4 + r;
            out[((size_t)b * NN + n) * CC + o] = acc[ji][r] + bo;
        }
    }
}
#undef XLD

// ---------------------------------------------------------------------------
// Host launch: 4 dispatches.
// Workspace (bf16): Ab 8 | xT 16 | xN 16 | y1T 16 | y1N 16 | y2N 16
//   | WpT 0.24  = 88.25 MB.
// ---------------------------------------------------------------------------
extern "C" void kernel_launch(void* const* d_in, const int* in_sizes, int n_in,
                              void* d_out, int out_size, void* d_ws, size_t ws_size,
                              hipStream_t stream) {
    const float* x  = (const float*)d_in[0];
    const float* E  = (const float*)d_in[1];
    const float* Wp = (const float*)d_in[2];
    const float* bp = (const float*)d_in[3];

    ushort_t* Ab  = (ushort_t*)d_ws;                    // [2048][2048]
    ushort_t* xT  = Ab + (size_t)NN * NN;               // [4096][2048]
    ushort_t* xN  = xT + (size_t)JJ * NN;               // [2048][4096]
    ushort_t* y1T = xN + (size_t)NN * JJ;               // [4096][2048]
    ushort_t* y1N = y1T + (size_t)JJ * NN;              // [2048][4096]
    ushort_t* y2N = y1N + (size_t)NN * JJ;              // [2048][4096]
    ushort_t* WpT = y2N + (size_t)NN * JJ;              // [30][64][64]
    float* out = (float*)d_out;

    prep_kernel<<<2 * NN + ED * KK, 256, 0, stream>>>(E, x, Wp, Ab, xT, xN, WpT);
    // y1 = A @ x : dual output (K-major + node-major)
    gemm_pipe<0><<<256, 512, 0, stream>>>(Ab, xT, nullptr, y1T, y1N);
    // y2 = 2 A @ y1 - x : node-major only
    gemm_pipe<1><<<256, 512, 0, stream>>>(Ab, y1T, xN, nullptr, y2N);
    out_kernel<<<NN, 256, 0, stream>>>(E, WpT, bp, xN, y1N, y2N, out);
}